// Round 1
// baseline (63.092 us; speedup 1.0000x reference)
//
#include <hip/hip_runtime.h>

#define N_EL 30
#define LAMBDA_COORD 5.0f
#define LAMBDA_NOOBJ 0.5f

__device__ __forceinline__ float iou_fn(const float* p, const float* t) {
    // corner-format boxes: (x1,y1,x2,y2)
    float ltx = fmaxf(p[0], t[0]);
    float lty = fmaxf(p[1], t[1]);
    float rbx = fminf(p[2], t[2]);
    float rby = fminf(p[3], t[3]);
    float w = fmaxf(rbx - ltx, 0.0f);
    float h = fmaxf(rby - lty, 0.0f);
    float inter = w * h;
    float a1 = (p[2] - p[0]) * (p[3] - p[1]);
    float a2 = (t[2] - t[0]) * (t[3] - t[1]);
    return inter / (a1 + a2 - inter + 1e-10f);
}

__global__ __launch_bounds__(256) void yolo_loss_kernel(
    const float* __restrict__ pred,
    const float* __restrict__ tgt,
    float* __restrict__ out,
    int n_cells)
{
    int cell = blockIdx.x * blockDim.x + threadIdx.x;
    float total = 0.0f;
    if (cell < n_cells) {
        const float2* P2 = reinterpret_cast<const float2*>(pred) + (size_t)cell * 15;
        const float2* T2 = reinterpret_cast<const float2*>(tgt)  + (size_t)cell * 15;
        float p[N_EL], t[N_EL];
        #pragma unroll
        for (int i = 0; i < 15; ++i) {
            float2 a = P2[i]; p[2*i] = a.x; p[2*i+1] = a.y;
            float2 b = T2[i]; t[2*i] = b.x; t[2*i+1] = b.y;
        }

        bool coord = (t[5] > 0.0f);
        bool noobj = (t[5] == 0.0f);

        // no-object confidence loss (conf slots 4 and 9)
        float d4 = p[4] - t[4];
        float d9 = p[9] - t[9];
        float noobj_loss = noobj ? (d4 * d4 + d9 * d9) : 0.0f;

        // class loss (elements 10..29) over object cells
        float cls = 0.0f;
        #pragma unroll
        for (int k = 10; k < 30; ++k) { float d = p[k] - t[k]; cls += d * d; }
        cls = coord ? cls : 0.0f;

        // responsible-box assignment via pairwise IoU (2 pred x 2 tgt boxes)
        float iou00 = iou_fn(p,     t);
        float iou01 = iou_fn(p,     t + 5);
        float iou10 = iou_fn(p + 5, t);
        float iou11 = iou_fn(p + 5, t + 5);
        // argmax over pred index, ties -> index 0 (jnp.argmax semantics)
        bool m0 = (iou10 > iou00);   // pred box chosen for target 0
        bool m1 = (iou11 > iou01);   // pred box chosen for target 1
        bool r0 = coord && ((!m0) || (!m1));
        bool r1 = coord && (m0 || m1);

        float contain = (r0 ? d4 * d4 : 0.0f) + (r1 ? d9 * d9 : 0.0f);

        float loc = 0.0f;
        #pragma unroll
        for (int k = 0; k < 4; ++k) { float d = p[k] - t[k];     loc += r0 ? d * d : 0.0f; }
        #pragma unroll
        for (int k = 5; k < 9; ++k) { float d = p[k] - t[k];     loc += r1 ? d * d : 0.0f; }

        total = LAMBDA_COORD * loc + contain + LAMBDA_NOOBJ * noobj_loss + cls;
    }

    // 64-lane wave reduction
    #pragma unroll
    for (int off = 32; off > 0; off >>= 1)
        total += __shfl_down(total, off, 64);

    __shared__ float ws[4];
    int lane = threadIdx.x & 63;
    int wid  = threadIdx.x >> 6;
    if (lane == 0) ws[wid] = total;
    __syncthreads();
    if (threadIdx.x == 0) {
        float s = ws[0] + ws[1] + ws[2] + ws[3];
        atomicAdd(out, s);
    }
}

extern "C" void kernel_launch(void* const* d_in, const int* in_sizes, int n_in,
                              void* d_out, int out_size, void* d_ws, size_t ws_size,
                              hipStream_t stream) {
    const float* pred = (const float*)d_in[0];
    const float* tgt  = (const float*)d_in[1];
    float* out = (float*)d_out;
    int n_cells = in_sizes[0] / N_EL;   // 16384 * 49 = 802816

    hipMemsetAsync(out, 0, sizeof(float), stream);

    const int block = 256;
    int grid = (n_cells + block - 1) / block;  // 3136
    yolo_loss_kernel<<<grid, block, 0, stream>>>(pred, tgt, out, n_cells);
}

// Round 2
// 60.857 us; speedup vs baseline: 1.0367x; 1.0367x over previous
//
#include <hip/hip_runtime.h>

#define N_EL 30
#define LAMBDA_COORD 5.0f
#define LAMBDA_NOOBJ 0.5f
#define CPB 256                    // cells per block
#define FLOATS_PER (CPB * N_EL)    // 7680 floats per tensor per block
#define VEC4_PER (FLOATS_PER / 4)  // 1920 float4 per tensor per block

__device__ __forceinline__ float iou_fn(const float* p, const float* t) {
    float ltx = fmaxf(p[0], t[0]);
    float lty = fmaxf(p[1], t[1]);
    float rbx = fminf(p[2], t[2]);
    float rby = fminf(p[3], t[3]);
    float w = fmaxf(rbx - ltx, 0.0f);
    float h = fmaxf(rby - lty, 0.0f);
    float inter = w * h;
    float a1 = (p[2] - p[0]) * (p[3] - p[1]);
    float a2 = (t[2] - t[0]) * (t[3] - t[1]);
    return inter / (a1 + a2 - inter + 1e-10f);
}

__global__ __launch_bounds__(256) void yolo_loss_kernel(
    const float* __restrict__ pred,
    const float* __restrict__ tgt,
    float* __restrict__ out)
{
    __shared__ float sp[FLOATS_PER];
    __shared__ float st[FLOATS_PER];

    const int tid = threadIdx.x;

    // ---- coalesced staging: 1920 float4 per tensor, 256 threads ----
    const float4* Pg = reinterpret_cast<const float4*>(pred) + (size_t)blockIdx.x * VEC4_PER;
    const float4* Tg = reinterpret_cast<const float4*>(tgt)  + (size_t)blockIdx.x * VEC4_PER;
    float4* sp4 = reinterpret_cast<float4*>(sp);
    float4* st4 = reinterpret_cast<float4*>(st);
    #pragma unroll
    for (int r = 0; r < VEC4_PER / 256; ++r) {       // 7.5 -> 7 full rounds
        int i = r * 256 + tid;
        sp4[i] = Pg[i];
        st4[i] = Tg[i];
    }
    {   // remaining 128 vectors (1792..1919): first 128 threads
        int i = 7 * 256 + tid;
        if (tid < VEC4_PER - 7 * 256) {
            sp4[i] = Pg[i];
            st4[i] = Tg[i];
        }
    }
    __syncthreads();

    // ---- per-cell compute from LDS ----
    float p[N_EL], t[N_EL];
    const float2* lp = reinterpret_cast<const float2*>(sp + tid * N_EL);
    const float2* lt = reinterpret_cast<const float2*>(st + tid * N_EL);
    #pragma unroll
    for (int i = 0; i < 15; ++i) {
        float2 a = lp[i]; p[2*i] = a.x; p[2*i+1] = a.y;
        float2 b = lt[i]; t[2*i] = b.x; t[2*i+1] = b.y;
    }

    bool coord = (t[5] > 0.0f);
    bool noobj = (t[5] == 0.0f);

    float d4 = p[4] - t[4];
    float d9 = p[9] - t[9];
    float noobj_loss = noobj ? (d4 * d4 + d9 * d9) : 0.0f;

    float cls = 0.0f;
    #pragma unroll
    for (int k = 10; k < 30; ++k) { float d = p[k] - t[k]; cls += d * d; }
    cls = coord ? cls : 0.0f;

    float iou00 = iou_fn(p,     t);
    float iou01 = iou_fn(p,     t + 5);
    float iou10 = iou_fn(p + 5, t);
    float iou11 = iou_fn(p + 5, t + 5);
    bool m0 = (iou10 > iou00);   // pred box index chosen for target 0 (tie -> 0)
    bool m1 = (iou11 > iou01);
    bool r0 = coord && ((!m0) || (!m1));
    bool r1 = coord && (m0 || m1);

    float contain = (r0 ? d4 * d4 : 0.0f) + (r1 ? d9 * d9 : 0.0f);

    float loc = 0.0f;
    #pragma unroll
    for (int k = 0; k < 4; ++k) { float d = p[k] - t[k]; loc += r0 ? d * d : 0.0f; }
    #pragma unroll
    for (int k = 5; k < 9; ++k) { float d = p[k] - t[k]; loc += r1 ? d * d : 0.0f; }

    float total = LAMBDA_COORD * loc + contain + LAMBDA_NOOBJ * noobj_loss + cls;

    // ---- 64-lane wave reduction, then cross-wave via LDS ----
    #pragma unroll
    for (int off = 32; off > 0; off >>= 1)
        total += __shfl_down(total, off, 64);

    __shared__ float ws[4];
    int lane = tid & 63;
    int wid  = tid >> 6;
    if (lane == 0) ws[wid] = total;
    __syncthreads();
    if (tid == 0) {
        atomicAdd(out, ws[0] + ws[1] + ws[2] + ws[3]);
    }
}

extern "C" void kernel_launch(void* const* d_in, const int* in_sizes, int n_in,
                              void* d_out, int out_size, void* d_ws, size_t ws_size,
                              hipStream_t stream) {
    const float* pred = (const float*)d_in[0];
    const float* tgt  = (const float*)d_in[1];
    float* out = (float*)d_out;
    int n_cells = in_sizes[0] / N_EL;          // 802816 = 256 * 3136
    int grid = n_cells / CPB;                  // 3136, exact

    hipMemsetAsync(out, 0, sizeof(float), stream);
    yolo_loss_kernel<<<grid, 256, 0, stream>>>(pred, tgt, out);
}

// Round 3
// 38.556 us; speedup vs baseline: 1.6364x; 1.5784x over previous
//
#include <hip/hip_runtime.h>

#define N_EL 30
#define LAMBDA_COORD 5.0f
#define LAMBDA_NOOBJ 0.5f
#define CPB 256                    // cells per block
#define FLOATS_PER (CPB * N_EL)    // 7680 floats per tensor per block
#define VEC4_PER (FLOATS_PER / 4)  // 1920 float4 per tensor per block

__device__ __forceinline__ float iou_fn(const float* p, const float* t) {
    float ltx = fmaxf(p[0], t[0]);
    float lty = fmaxf(p[1], t[1]);
    float rbx = fminf(p[2], t[2]);
    float rby = fminf(p[3], t[3]);
    float w = fmaxf(rbx - ltx, 0.0f);
    float h = fmaxf(rby - lty, 0.0f);
    float inter = w * h;
    float a1 = (p[2] - p[0]) * (p[3] - p[1]);
    float a2 = (t[2] - t[0]) * (t[3] - t[1]);
    return inter / (a1 + a2 - inter + 1e-10f);
}

__global__ __launch_bounds__(256) void yolo_loss_main(
    const float* __restrict__ pred,
    const float* __restrict__ tgt,
    float* __restrict__ partials)
{
    __shared__ float sp[FLOATS_PER];
    __shared__ float st[FLOATS_PER];

    const int tid = threadIdx.x;

    // ---- coalesced staging: 1920 float4 per tensor, 256 threads ----
    const float4* Pg = reinterpret_cast<const float4*>(pred) + (size_t)blockIdx.x * VEC4_PER;
    const float4* Tg = reinterpret_cast<const float4*>(tgt)  + (size_t)blockIdx.x * VEC4_PER;
    float4* sp4 = reinterpret_cast<float4*>(sp);
    float4* st4 = reinterpret_cast<float4*>(st);
    #pragma unroll
    for (int r = 0; r < VEC4_PER / 256; ++r) {       // 7 full rounds
        int i = r * 256 + tid;
        sp4[i] = Pg[i];
        st4[i] = Tg[i];
    }
    {   // remaining 128 vectors: first 128 threads
        int i = 7 * 256 + tid;
        if (tid < VEC4_PER - 7 * 256) {
            sp4[i] = Pg[i];
            st4[i] = Tg[i];
        }
    }
    __syncthreads();

    // ---- per-cell compute from LDS ----
    float p[N_EL], t[N_EL];
    const float2* lp = reinterpret_cast<const float2*>(sp + tid * N_EL);
    const float2* lt = reinterpret_cast<const float2*>(st + tid * N_EL);
    #pragma unroll
    for (int i = 0; i < 15; ++i) {
        float2 a = lp[i]; p[2*i] = a.x; p[2*i+1] = a.y;
        float2 b = lt[i]; t[2*i] = b.x; t[2*i+1] = b.y;
    }

    bool coord = (t[5] > 0.0f);
    bool noobj = (t[5] == 0.0f);

    float d4 = p[4] - t[4];
    float d9 = p[9] - t[9];
    float noobj_loss = noobj ? (d4 * d4 + d9 * d9) : 0.0f;

    float cls = 0.0f;
    #pragma unroll
    for (int k = 10; k < 30; ++k) { float d = p[k] - t[k]; cls += d * d; }
    cls = coord ? cls : 0.0f;

    float iou00 = iou_fn(p,     t);
    float iou01 = iou_fn(p,     t + 5);
    float iou10 = iou_fn(p + 5, t);
    float iou11 = iou_fn(p + 5, t + 5);
    bool m0 = (iou10 > iou00);   // pred box chosen for target 0 (tie -> 0)
    bool m1 = (iou11 > iou01);
    bool r0 = coord && ((!m0) || (!m1));
    bool r1 = coord && (m0 || m1);

    float contain = (r0 ? d4 * d4 : 0.0f) + (r1 ? d9 * d9 : 0.0f);

    float loc = 0.0f;
    #pragma unroll
    for (int k = 0; k < 4; ++k) { float d = p[k] - t[k]; loc += r0 ? d * d : 0.0f; }
    #pragma unroll
    for (int k = 5; k < 9; ++k) { float d = p[k] - t[k]; loc += r1 ? d * d : 0.0f; }

    float total = LAMBDA_COORD * loc + contain + LAMBDA_NOOBJ * noobj_loss + cls;

    // ---- 64-lane wave reduction, then cross-wave via LDS ----
    #pragma unroll
    for (int off = 32; off > 0; off >>= 1)
        total += __shfl_down(total, off, 64);

    __shared__ float ws[4];
    int lane = tid & 63;
    int wid  = tid >> 6;
    if (lane == 0) ws[wid] = total;
    __syncthreads();
    if (tid == 0) {
        partials[blockIdx.x] = ws[0] + ws[1] + ws[2] + ws[3];   // plain store, no atomic
    }
}

__global__ __launch_bounds__(256) void yolo_loss_final(
    const float* __restrict__ partials,
    float* __restrict__ out,
    int n)
{
    const int tid = threadIdx.x;
    float s = 0.0f;
    for (int i = tid; i < n; i += 256) s += partials[i];

    #pragma unroll
    for (int off = 32; off > 0; off >>= 1)
        s += __shfl_down(s, off, 64);

    __shared__ float ws[4];
    int lane = tid & 63;
    int wid  = tid >> 6;
    if (lane == 0) ws[wid] = s;
    __syncthreads();
    if (tid == 0) out[0] = ws[0] + ws[1] + ws[2] + ws[3];
}

extern "C" void kernel_launch(void* const* d_in, const int* in_sizes, int n_in,
                              void* d_out, int out_size, void* d_ws, size_t ws_size,
                              hipStream_t stream) {
    const float* pred = (const float*)d_in[0];
    const float* tgt  = (const float*)d_in[1];
    float* out = (float*)d_out;
    float* partials = (float*)d_ws;
    int n_cells = in_sizes[0] / N_EL;          // 802816 = 256 * 3136
    int grid = n_cells / CPB;                  // 3136, exact

    yolo_loss_main<<<grid, 256, 0, stream>>>(pred, tgt, partials);
    yolo_loss_final<<<1, 256, 0, stream>>>(partials, out, grid);
}

// Round 4
// 37.227 us; speedup vs baseline: 1.6948x; 1.0357x over previous
//
#include <hip/hip_runtime.h>

#define N_EL 30
#define LAMBDA_COORD 5.0f
#define LAMBDA_NOOBJ 0.5f
#define CPB 256                    // cells per block
#define FLOATS_PER (CPB * N_EL)    // 7680 floats per tensor per block
#define VEC4_PER (FLOATS_PER / 4)  // 1920 float4 per tensor per block

typedef const __attribute__((address_space(1))) void gas_void;
typedef __attribute__((address_space(3))) void las_void;

__device__ __forceinline__ float iou_fn(const float* p, const float* t) {
    float ltx = fmaxf(p[0], t[0]);
    float lty = fmaxf(p[1], t[1]);
    float rbx = fminf(p[2], t[2]);
    float rby = fminf(p[3], t[3]);
    float w = fmaxf(rbx - ltx, 0.0f);
    float h = fmaxf(rby - lty, 0.0f);
    float inter = w * h;
    float a1 = (p[2] - p[0]) * (p[3] - p[1]);
    float a2 = (t[2] - t[0]) * (t[3] - t[1]);
    return inter / (a1 + a2 - inter + 1e-10f);
}

__global__ __launch_bounds__(256) void yolo_loss_main(
    const float* __restrict__ pred,
    const float* __restrict__ tgt,
    float* __restrict__ partials)
{
    __shared__ float sp[FLOATS_PER];
    __shared__ float st[FLOATS_PER];

    const int tid  = threadIdx.x;
    const int lane = tid & 63;
    const int wid  = tid >> 6;

    // ---- coalesced staging via direct global->LDS DMA (no VGPR roundtrip) ----
    // layout is linear: LDS float4 slot i <- G[block_base + i]; per wave the
    // dest is wave-uniform base + lane*16 which is exactly gload_lds semantics.
    const float4* Pg = reinterpret_cast<const float4*>(pred) + (size_t)blockIdx.x * VEC4_PER;
    const float4* Tg = reinterpret_cast<const float4*>(tgt)  + (size_t)blockIdx.x * VEC4_PER;
    float4* sp4 = reinterpret_cast<float4*>(sp);
    float4* st4 = reinterpret_cast<float4*>(st);

    #pragma unroll
    for (int r = 0; r < 7; ++r) {              // 7 full rounds of 256 vectors
        int i     = r * 256 + tid;             // per-lane global index
        int wbase = r * 256 + (wid << 6);      // wave-uniform LDS base (float4 slots)
        __builtin_amdgcn_global_load_lds((gas_void*)(Pg + i), (las_void*)(sp4 + wbase), 16, 0, 0);
        __builtin_amdgcn_global_load_lds((gas_void*)(Tg + i), (las_void*)(st4 + wbase), 16, 0, 0);
    }
    if (wid < 2) {                             // remaining 128 vectors (waves 0,1)
        int i     = 7 * 256 + tid;
        int wbase = 7 * 256 + (wid << 6);
        __builtin_amdgcn_global_load_lds((gas_void*)(Pg + i), (las_void*)(sp4 + wbase), 16, 0, 0);
        __builtin_amdgcn_global_load_lds((gas_void*)(Tg + i), (las_void*)(st4 + wbase), 16, 0, 0);
    }
    __syncthreads();   // compiler emits vmcnt(0) drain + barrier

    // ---- per-cell compute from LDS ----
    float p[N_EL], t[N_EL];
    const float2* lp = reinterpret_cast<const float2*>(sp + tid * N_EL);
    const float2* lt = reinterpret_cast<const float2*>(st + tid * N_EL);
    #pragma unroll
    for (int i = 0; i < 15; ++i) {
        float2 a = lp[i]; p[2*i] = a.x; p[2*i+1] = a.y;
        float2 b = lt[i]; t[2*i] = b.x; t[2*i+1] = b.y;
    }

    bool coord = (t[5] > 0.0f);
    bool noobj = (t[5] == 0.0f);

    float d4 = p[4] - t[4];
    float d9 = p[9] - t[9];
    float noobj_loss = noobj ? (d4 * d4 + d9 * d9) : 0.0f;

    float cls = 0.0f;
    #pragma unroll
    for (int k = 10; k < 30; ++k) { float d = p[k] - t[k]; cls += d * d; }
    cls = coord ? cls : 0.0f;

    float iou00 = iou_fn(p,     t);
    float iou01 = iou_fn(p,     t + 5);
    float iou10 = iou_fn(p + 5, t);
    float iou11 = iou_fn(p + 5, t + 5);
    bool m0 = (iou10 > iou00);   // pred box chosen for target 0 (tie -> 0)
    bool m1 = (iou11 > iou01);
    bool r0 = coord && ((!m0) || (!m1));
    bool r1 = coord && (m0 || m1);

    float contain = (r0 ? d4 * d4 : 0.0f) + (r1 ? d9 * d9 : 0.0f);

    float loc = 0.0f;
    #pragma unroll
    for (int k = 0; k < 4; ++k) { float d = p[k] - t[k]; loc += r0 ? d * d : 0.0f; }
    #pragma unroll
    for (int k = 5; k < 9; ++k) { float d = p[k] - t[k]; loc += r1 ? d * d : 0.0f; }

    float total = LAMBDA_COORD * loc + contain + LAMBDA_NOOBJ * noobj_loss + cls;

    // ---- 64-lane wave reduction, then cross-wave via LDS ----
    #pragma unroll
    for (int off = 32; off > 0; off >>= 1)
        total += __shfl_down(total, off, 64);

    __shared__ float ws[4];
    if (lane == 0) ws[wid] = total;
    __syncthreads();
    if (tid == 0) {
        partials[blockIdx.x] = ws[0] + ws[1] + ws[2] + ws[3];   // plain store, no atomic
    }
}

__global__ __launch_bounds__(256) void yolo_loss_final(
    const float* __restrict__ partials,
    float* __restrict__ out,
    int n)
{
    const int tid = threadIdx.x;
    float s = 0.0f;
    for (int i = tid; i < n; i += 256) s += partials[i];

    #pragma unroll
    for (int off = 32; off > 0; off >>= 1)
        s += __shfl_down(s, off, 64);

    __shared__ float ws[4];
    int lane = tid & 63;
    int wid  = tid >> 6;
    if (lane == 0) ws[wid] = s;
    __syncthreads();
    if (tid == 0) out[0] = ws[0] + ws[1] + ws[2] + ws[3];
}

extern "C" void kernel_launch(void* const* d_in, const int* in_sizes, int n_in,
                              void* d_out, int out_size, void* d_ws, size_t ws_size,
                              hipStream_t stream) {
    const float* pred = (const float*)d_in[0];
    const float* tgt  = (const float*)d_in[1];
    float* out = (float*)d_out;
    float* partials = (float*)d_ws;
    int n_cells = in_sizes[0] / N_EL;          // 802816 = 256 * 3136
    int grid = n_cells / CPB;                  // 3136, exact

    yolo_loss_main<<<grid, 256, 0, stream>>>(pred, tgt, partials);
    yolo_loss_final<<<1, 256, 0, stream>>>(partials, out, grid);
}